// Round 2
// baseline (414.385 us; speedup 1.0000x reference)
//
#include <hip/hip_runtime.h>
#include <hip/hip_bf16.h>
#include <stdint.h>

typedef __hip_bfloat16 bf16;
typedef __attribute__((ext_vector_type(8))) short v8s;   // 8 bf16 in 4 VGPRs
typedef __attribute__((ext_vector_type(4))) float v4f;   // MFMA C/D frag

__device__ __forceinline__ bf16 tob(float x) { return __float2bfloat16(x); }
__device__ __forceinline__ float tof(bf16 x) { return __bfloat162float(x); }

// async global->LDS, 16B per lane. Direct pointer casts -> addrspacecast
// (NOT an integer truncation of the flat address — that was R1's latent bug).
__device__ __forceinline__ void gload16(const void* g, void* l) {
  __builtin_amdgcn_global_load_lds(
      (const __attribute__((address_space(1))) uint32_t*)g,
      (__attribute__((address_space(3))) uint32_t*)l,
      16, 0, 0);
}

// ---------------- h1 = relu(fea @ W_l1 + b_l1)   (8,1024) fp32 ----------------
__global__ void k_lin1(const float* __restrict__ fea, const float* __restrict__ W,
                       const float* __restrict__ bias, float* __restrict__ h1) {
  int idx = blockIdx.x * 256 + threadIdx.x;      // 8192
  int b = idx >> 10, n = idx & 1023;
  const float* fr = fea + (b << 10);
  float acc = bias[n];
#pragma unroll 8
  for (int k = 0; k < 1024; ++k)
    acc = fmaf(fr[k], W[k * 1024 + n], acc);
  h1[idx] = fmaxf(acc, 0.f);
}

// ---------------- x = h1 @ W_l2 + b_l2   (8,3072) fp32; writes d_out + ws ----------------
__global__ void k_lin2(const float* __restrict__ h1, const float* __restrict__ W,
                       const float* __restrict__ bias, float* __restrict__ xf,
                       float* __restrict__ xout) {
  int idx = blockIdx.x * 256 + threadIdx.x;      // 24576
  int b = idx / 3072, n = idx - b * 3072;
  const float* hr = h1 + (b << 10);
  float acc = bias[n];
#pragma unroll 8
  for (int k = 0; k < 1024; ++k)
    acc = fmaf(hr[k], W[k * 3072 + n], acc);
  xf[idx] = acc;
  xout[idx] = acc;
}

// ---------------- gp[b,n] = fea[b] @ W_c1[5:,n] + b_c1[n]   (8,512) fp32 ----------------
__global__ void k_gp(const float* __restrict__ fea, const float* __restrict__ Wc1,
                     const float* __restrict__ bc1, float* __restrict__ gp) {
  int idx = blockIdx.x * 256 + threadIdx.x;      // 4096
  int b = idx >> 9, n = idx & 511;
  const float* fr = fea + (b << 10);
  float acc = bc1[n];
#pragma unroll 8
  for (int k = 0; k < 1024; ++k)
    acc = fmaf(fr[k], Wc1[(5 + k) * 512 + n], acc);
  gp[idx] = acc;
}

// ---------------- W2T[n,k] = bf16(W_c2[k,n])  (512,512), LDS-tiled ----------------
__global__ void k_w2t(const float* __restrict__ W, bf16* __restrict__ WT) {
  __shared__ float tile[32][33];
  int bx = blockIdx.x & 15, by = blockIdx.x >> 4;   // bx: n-tile, by: k-tile
  int c = threadIdx.x & 31, r8 = threadIdx.x >> 5;  // 8 rows per pass
#pragma unroll
  for (int i = 0; i < 4; ++i) {
    int r = r8 + i * 8;
    tile[r][c] = W[(by * 32 + r) * 512 + bx * 32 + c];
  }
  __syncthreads();
#pragma unroll
  for (int i = 0; i < 4; ++i) {
    int r = r8 + i * 8;
    WT[(size_t)(bx * 32 + r) * 512 + by * 32 + c] = tob(tile[c][r]);
  }
}

// ---------------- R[m,k] = bf16(relu(gp + grid·W01 + x·W234))  (131072,512) ----------------
__global__ void k_R(const float* __restrict__ gp, const float* __restrict__ xf,
                    const float* __restrict__ Wc1, bf16* __restrict__ R) {
  int idx = blockIdx.x * 256 + threadIdx.x;      // 8388608 threads, 8 k each
  int m = idx >> 6;
  int kb = (idx & 63) << 3;
  int b = m >> 14, f = m & 16383, c = f >> 4, g = f & 15;
  float gx = -0.05f + (float)(g & 3) * (0.1f / 3.0f);
  float gy = -0.05f + (float)(g >> 2) * (0.1f / 3.0f);
  const float* xp = xf + (b * 1024 + c) * 3;
  float x0 = xp[0], x1 = xp[1], x2 = xp[2];
  const float* gpr = gp + (b << 9) + kb;
  const float* w0 = Wc1 + 0 * 512 + kb;
  const float* w1 = Wc1 + 1 * 512 + kb;
  const float* w2 = Wc1 + 2 * 512 + kb;
  const float* w3 = Wc1 + 3 * 512 + kb;
  const float* w4 = Wc1 + 4 * 512 + kb;
  union { bf16 h[8]; uint4 u; } out;
#pragma unroll
  for (int i = 0; i < 8; ++i) {
    float v = gpr[i];
    v = fmaf(gx, w0[i], v);
    v = fmaf(gy, w1[i], v);
    v = fmaf(x0, w2[i], v);
    v = fmaf(x1, w3[i], v);
    v = fmaf(x2, w4[i], v);
    out.h[i] = tob(fmaxf(v, 0.f));
  }
  *(uint4*)(R + (size_t)m * 512 + kb) = out.u;
}

// ---------------- fused conv2 GEMM (bf16 MFMA) + conv3 epilogue ----------------
// 1024 blocks: rows m0..m0+127 of R (M=131072), K=512, N=512 in 4 chunks of 128.
__global__ __launch_bounds__(256, 2)
void k_gemm(const bf16* __restrict__ R, const bf16* __restrict__ W2T,
            const float* __restrict__ bc2, const float* __restrict__ Wc3,
            const float* __restrict__ bc3, const float* __restrict__ xf,
            float* __restrict__ fine) {
  __shared__ __align__(16) bf16 As[128 * 32];
  __shared__ __align__(16) bf16 Bs[128 * 32];
  __shared__ float facc[128][3];
  const int t = threadIdx.x;
  const int m0 = blockIdx.x * 128;
  if (t < 128) { facc[t][0] = 0.f; facc[t][1] = 0.f; facc[t][2] = 0.f; }
  const int w = t >> 6, l = t & 63, q = l >> 4, lm = l & 15;
  const int wm = w >> 1, wn = w & 1;
  const int arow = t >> 2;                 // staging row (of 64)
  const int acolb = (t & 3) << 4;          // staging byte col
  const char* Ra = (const char*)R + (size_t)(m0 + arow) * 1024 + acolb;
  const char* Rb = Ra + 64 * 1024;
  char* Asb = (char*)As;
  char* Bsb = (char*)Bs;

  float part[4][4][3];
#pragma unroll
  for (int mi = 0; mi < 4; ++mi)
#pragma unroll
    for (int r = 0; r < 4; ++r) { part[mi][r][0] = 0.f; part[mi][r][1] = 0.f; part[mi][r][2] = 0.f; }

#pragma unroll 1
  for (int chunk = 0; chunk < 4; ++chunk) {
    const int n0 = chunk * 128;
    const char* Wa = (const char*)W2T + (size_t)(n0 + arow) * 1024 + acolb;
    const char* Wb = Wa + 64 * 1024;
    v4f acc[4][4];
#pragma unroll
    for (int mi = 0; mi < 4; ++mi)
#pragma unroll
      for (int ni = 0; ni < 4; ++ni) acc[mi][ni] = (v4f){0.f, 0.f, 0.f, 0.f};

    for (int kt = 0; kt < 16; ++kt) {
      const int kb = kt << 6;              // 32 bf16 = 64B per row per step
      __syncthreads();
      gload16(Ra + kb, Asb + t * 16);
      gload16(Rb + kb, Asb + 4096 + t * 16);
      gload16(Wa + kb, Bsb + t * 16);
      gload16(Wb + kb, Bsb + 4096 + t * 16);
      __syncthreads();
      v8s af[4], bfr[4];
#pragma unroll
      for (int mi = 0; mi < 4; ++mi)
        af[mi] = *(const v8s*)(Asb + ((wm * 64 + mi * 16 + lm) << 6) + (q << 4));
#pragma unroll
      for (int ni = 0; ni < 4; ++ni)
        bfr[ni] = *(const v8s*)(Bsb + ((wn * 64 + ni * 16 + lm) << 6) + (q << 4));
#pragma unroll
      for (int mi = 0; mi < 4; ++mi)
#pragma unroll
        for (int ni = 0; ni < 4; ++ni)
          acc[mi][ni] = __builtin_amdgcn_mfma_f32_16x16x32_bf16(af[mi], bfr[ni], acc[mi][ni], 0, 0, 0);
    }

    // epilogue: h2 = relu(acc + b_c2[n]); per-lane conv3 partials over this lane's cols
#pragma unroll
    for (int ni = 0; ni < 4; ++ni) {
      const int n = n0 + wn * 64 + ni * 16 + lm;
      const float bv = bc2[n];
      const float w30 = Wc3[n * 3 + 0];
      const float w31 = Wc3[n * 3 + 1];
      const float w32 = Wc3[n * 3 + 2];
#pragma unroll
      for (int mi = 0; mi < 4; ++mi)
#pragma unroll
        for (int r = 0; r < 4; ++r) {
          float v = fmaxf(acc[mi][ni][r] + bv, 0.f);
          part[mi][r][0] = fmaf(v, w30, part[mi][r][0]);
          part[mi][r][1] = fmaf(v, w31, part[mi][r][1]);
          part[mi][r][2] = fmaf(v, w32, part[mi][r][2]);
        }
    }
  }

  // reduce the 16 lm-lanes of each quad, then across wn waves via LDS atomics
#pragma unroll
  for (int mi = 0; mi < 4; ++mi)
#pragma unroll
    for (int r = 0; r < 4; ++r)
#pragma unroll
      for (int j = 0; j < 3; ++j) {
        float v = part[mi][r][j];
        v += __shfl_xor(v, 1);
        v += __shfl_xor(v, 2);
        v += __shfl_xor(v, 4);
        v += __shfl_xor(v, 8);
        if (lm == 0) atomicAdd(&facc[wm * 64 + mi * 16 + q * 4 + r][j], v);
      }
  __syncthreads();
  if (t < 128) {
    const int m = m0 + t;
    const int b = m >> 14, c = (m & 16383) >> 4;
    const float* xp = xf + (b * 1024 + c) * 3;
#pragma unroll
    for (int j = 0; j < 3; ++j)
      fine[(size_t)m * 3 + j] = facc[t][j] + bc3[j] + xp[j];
  }
}

extern "C" void kernel_launch(void* const* d_in, const int* in_sizes, int n_in,
                              void* d_out, int out_size, void* d_ws, size_t ws_size,
                              hipStream_t stream) {
  const float* fea = (const float*)d_in[0];
  const float* Wl1 = (const float*)d_in[1];
  const float* bl1 = (const float*)d_in[2];
  const float* Wl2 = (const float*)d_in[3];
  const float* bl2 = (const float*)d_in[4];
  const float* Wc1 = (const float*)d_in[5];
  const float* bc1 = (const float*)d_in[6];
  const float* Wc2 = (const float*)d_in[7];
  const float* bc2 = (const float*)d_in[8];
  const float* Wc3 = (const float*)d_in[9];
  const float* bc3 = (const float*)d_in[10];
  float* xout = (float*)d_out;                // (8,1024,3)
  float* fine = (float*)d_out + 24576;        // (8,16384,3)
  char* ws = (char*)d_ws;
  float* h1  = (float*)ws;                    // 32 KB
  float* xf  = (float*)(ws + 32768);          // 96 KB
  float* gp  = (float*)(ws + 131072);         // 16 KB
  bf16*  W2T = (bf16*)(ws + 147456);          // 512 KB
  bf16*  R   = (bf16*)(ws + 1048576);         // 128 MB

  k_lin1<<<32, 256, 0, stream>>>(fea, Wl1, bl1, h1);
  k_lin2<<<96, 256, 0, stream>>>(h1, Wl2, bl2, xf, xout);
  k_gp<<<16, 256, 0, stream>>>(fea, Wc1, bc1, gp);
  k_w2t<<<256, 256, 0, stream>>>(Wc2, W2T);
  k_R<<<32768, 256, 0, stream>>>(gp, xf, Wc1, R);
  k_gemm<<<1024, 256, 0, stream>>>(R, W2T, bc2, Wc3, bc3, xf, fine);
}

// Round 3
// 253.366 us; speedup vs baseline: 1.6355x; 1.6355x over previous
//
#include <hip/hip_runtime.h>
#include <hip/hip_bf16.h>
#include <stdint.h>

typedef __hip_bfloat16 bf16;
typedef __attribute__((ext_vector_type(8))) short v8s;   // 8 bf16 in 4 VGPRs
typedef __attribute__((ext_vector_type(4))) float v4f;   // MFMA C/D frag

__device__ __forceinline__ bf16 tob(float x) { return __float2bfloat16(x); }

// async global->LDS, 16B per lane; LDS dest must be wave-uniform base + lane*16
__device__ __forceinline__ void gload16(const void* g, void* l) {
  __builtin_amdgcn_global_load_lds(
      (const __attribute__((address_space(1))) uint32_t*)g,
      (__attribute__((address_space(3))) uint32_t*)l,
      16, 0, 0);
}

// ============ k-split small GEMMs: block = 16 outputs x 16 k-slices ============
// h1 = relu(fea @ W_l1 + b_l1)   (8,1024), K=1024
__global__ void k_lin1(const float* __restrict__ fea, const float* __restrict__ W,
                       const float* __restrict__ bias, float* __restrict__ h1) {
  __shared__ float red[256];
  const int nl = threadIdx.x & 15, ks = threadIdx.x >> 4;
  const int o = blockIdx.x * 16 + nl;            // 0..8191, same b within block
  const int b = o >> 10, n = o & 1023;
  const float* fr = fea + (b << 10) + ks * 64;
  const float* wp = W + (size_t)(ks * 64) * 1024 + n;
  float acc = 0.f;
#pragma unroll 8
  for (int j = 0; j < 64; ++j)
    acc = fmaf(fr[j], wp[(size_t)j * 1024], acc);
  red[threadIdx.x] = acc;
  __syncthreads();
  if (threadIdx.x < 16) {
    float s = bias[n];
#pragma unroll
    for (int i = 0; i < 16; ++i) s += red[i * 16 + threadIdx.x];
    h1[o] = fmaxf(s, 0.f);
  }
}

// x = h1 @ W_l2 + b_l2   (8,3072), K=1024 -> xf (ws) + xout (d_out)
__global__ void k_lin2(const float* __restrict__ h1, const float* __restrict__ W,
                       const float* __restrict__ bias, float* __restrict__ xf,
                       float* __restrict__ xout) {
  __shared__ float red[256];
  const int nl = threadIdx.x & 15, ks = threadIdx.x >> 4;
  const int o = blockIdx.x * 16 + nl;            // 0..24575, same b within block
  const int b = o / 3072, n = o - b * 3072;
  const float* hr = h1 + (b << 10) + ks * 64;
  const float* wp = W + (size_t)(ks * 64) * 3072 + n;
  float acc = 0.f;
#pragma unroll 8
  for (int j = 0; j < 64; ++j)
    acc = fmaf(hr[j], wp[(size_t)j * 3072], acc);
  red[threadIdx.x] = acc;
  __syncthreads();
  if (threadIdx.x < 16) {
    float s = bias[n];
#pragma unroll
    for (int i = 0; i < 16; ++i) s += red[i * 16 + threadIdx.x];
    xf[o] = s;
    xout[o] = s;
  }
}

// gp[b,n] = fea[b] @ W_c1[5:,n] + b_c1[n]   (8,512), K=1024
__global__ void k_gp(const float* __restrict__ fea, const float* __restrict__ Wc1,
                     const float* __restrict__ bc1, float* __restrict__ gp) {
  __shared__ float red[256];
  const int nl = threadIdx.x & 15, ks = threadIdx.x >> 4;
  const int o = blockIdx.x * 16 + nl;            // 0..4095
  const int b = o >> 9, n = o & 511;
  const float* fr = fea + (b << 10) + ks * 64;
  const float* wp = Wc1 + (size_t)(5 + ks * 64) * 512 + n;
  float acc = 0.f;
#pragma unroll 8
  for (int j = 0; j < 64; ++j)
    acc = fmaf(fr[j], wp[(size_t)j * 512], acc);
  red[threadIdx.x] = acc;
  __syncthreads();
  if (threadIdx.x < 16) {
    float s = bc1[n];
#pragma unroll
    for (int i = 0; i < 16; ++i) s += red[i * 16 + threadIdx.x];
    gp[o] = s;
  }
}

// W2T[n,k] = bf16(W_c2[k,n])  (512,512), LDS-tiled
__global__ void k_w2t(const float* __restrict__ W, bf16* __restrict__ WT) {
  __shared__ float tile[32][33];
  int bx = blockIdx.x & 15, by = blockIdx.x >> 4;
  int c = threadIdx.x & 31, r8 = threadIdx.x >> 5;
#pragma unroll
  for (int i = 0; i < 4; ++i) {
    int r = r8 + i * 8;
    tile[r][c] = W[(by * 32 + r) * 512 + bx * 32 + c];
  }
  __syncthreads();
#pragma unroll
  for (int i = 0; i < 4; ++i) {
    int r = r8 + i * 8;
    WT[(size_t)(bx * 32 + r) * 512 + by * 32 + c] = tob(tile[c][r]);
  }
}

// ============ fused conv1+conv2 GEMM + conv3 epilogue ============
// 1024 blocks x 512 threads. Block: rows m0..m0+127, full N=512, K=512, BK=32.
// A-tile computed on the fly (rank-6 conv1 factorization), B staged via gload16.
// Double-buffered: at 1 block/CU there is no sibling block to hide the barrier
// drain, so stage(kt+1) is issued between the barrier and the MFMAs of kt.
__global__ __launch_bounds__(512, 2)
void k_gemm(const bf16* __restrict__ W2T, const float* __restrict__ Wc1,
            const float* __restrict__ gp, const float* __restrict__ xf,
            const float* __restrict__ bc2, const float* __restrict__ Wc3,
            const float* __restrict__ bc3, float* __restrict__ fine) {
  __shared__ __align__(16) bf16 As[2][128 * 32];   // 2 x 8 KB
  __shared__ __align__(16) bf16 Bs[2][512 * 32];   // 2 x 32 KB
  __shared__ float facc[128][3];
  const int t = threadIdx.x;
  const int m0 = blockIdx.x * 128;
  const int w = t >> 6, l = t & 63, q = l >> 4, lm = l & 15;
  const int wr = (w >> 2) * 64;          // wave output-row base (0 or 64)
  const int wc = (w & 3) * 128;          // wave output-col base

  if (t < 384) ((float*)facc)[t] = 0.f;

  // ---- A-compute role: thread -> (row arow, k-subgroup cg of 8) ----
  const int arow = t >> 2, cg = t & 3;
  const int m = m0 + arow;
  const int b = m >> 14;                 // batch, uniform per block
  const int f = m & 16383;
  const int c = f >> 4, g = f & 15;
  const float gx = -0.05f + (float)(g & 3) * (0.1f / 3.0f);
  const float gy = -0.05f + (float)(g >> 2) * (0.1f / 3.0f);
  const float* xp = xf + (b * 1024 + c) * 3;
  const float x0 = xp[0], x1 = xp[1], x2 = xp[2];
  const float* gpr = gp + (b << 9);
  char* awr = (char*)As + arow * 64 + cg * 16;     // + buf*8192

  // ---- B staging role: wave stages rows [w*64, w*64+64), 4 gload16/thread ----
  const char* bsrc = (const char*)W2T + (size_t)(w * 64 + (l >> 2)) * 1024 + (l & 3) * 16;
  char* bdst = (char*)Bs + w * 4096 + l * 16;      // + buf*32768 + i*1024

  v4f acc[4][8];
#pragma unroll
  for (int mi = 0; mi < 4; ++mi)
#pragma unroll
    for (int ni = 0; ni < 8; ++ni) acc[mi][ni] = (v4f){0.f, 0.f, 0.f, 0.f};

  auto stage = [&](int kt, int buf) {
    // B first: get the async loads in flight
    const char* src = bsrc + kt * 64;
    char* dst = bdst + buf * 32768;
#pragma unroll
    for (int i = 0; i < 4; ++i)
      gload16(src + (size_t)i * 16384, dst + i * 1024);
    // A: compute 8 elems (1 row x 8 k), two half-passes to limit live temps
    const int kk = kt * 32 + cg * 8;
    union { bf16 h[8]; uint4 u; } o;
#pragma unroll
    for (int h = 0; h < 2; ++h) {
      const int kb = kk + h * 4;
      float4 gv = *(const float4*)(gpr + kb);
      float4 a0 = *(const float4*)(Wc1 + 0 * 512 + kb);
      float4 a1 = *(const float4*)(Wc1 + 1 * 512 + kb);
      float4 a2 = *(const float4*)(Wc1 + 2 * 512 + kb);
      float4 a3 = *(const float4*)(Wc1 + 3 * 512 + kb);
      float4 a4 = *(const float4*)(Wc1 + 4 * 512 + kb);
#pragma unroll
      for (int j = 0; j < 4; ++j) {
        float v = ((const float*)&gv)[j];
        v = fmaf(gx, ((const float*)&a0)[j], v);
        v = fmaf(gy, ((const float*)&a1)[j], v);
        v = fmaf(x0, ((const float*)&a2)[j], v);
        v = fmaf(x1, ((const float*)&a3)[j], v);
        v = fmaf(x2, ((const float*)&a4)[j], v);
        o.h[h * 4 + j] = tob(fmaxf(v, 0.f));
      }
    }
    *(uint4*)(awr + buf * 8192) = o.u;
  };

  stage(0, 0);

#pragma unroll 2
  for (int kt = 0; kt < 16; ++kt) {
    const int buf = kt & 1;
    __syncthreads();                     // stage(kt,buf) complete on all waves
    if (kt < 15) stage(kt + 1, buf ^ 1); // prefetch next tile (other buffer)
    const char* ab = (const char*)As + buf * 8192;
    const char* bb = (const char*)Bs + buf * 32768;
    v8s af[4], bf8[8];
#pragma unroll
    for (int mi = 0; mi < 4; ++mi)
      af[mi] = *(const v8s*)(ab + (wr + mi * 16 + lm) * 64 + q * 16);
#pragma unroll
    for (int ni = 0; ni < 8; ++ni)
      bf8[ni] = *(const v8s*)(bb + (wc + ni * 16 + lm) * 64 + q * 16);
#pragma unroll
    for (int mi = 0; mi < 4; ++mi)
#pragma unroll
      for (int ni = 0; ni < 8; ++ni)
        acc[mi][ni] = __builtin_amdgcn_mfma_f32_16x16x32_bf16(af[mi], bf8[ni], acc[mi][ni], 0, 0, 0);
  }

  // ---- epilogue: h2 = relu(acc + b_c2); fine partials via Wc3 ----
  float part[4][4][3];
#pragma unroll
  for (int mi = 0; mi < 4; ++mi)
#pragma unroll
    for (int r = 0; r < 4; ++r) { part[mi][r][0] = 0.f; part[mi][r][1] = 0.f; part[mi][r][2] = 0.f; }
#pragma unroll
  for (int ni = 0; ni < 8; ++ni) {
    const int n = wc + ni * 16 + lm;
    const float bv = bc2[n];
    const float w30 = Wc3[n * 3 + 0];
    const float w31 = Wc3[n * 3 + 1];
    const float w32 = Wc3[n * 3 + 2];
#pragma unroll
    for (int mi = 0; mi < 4; ++mi)
#pragma unroll
      for (int r = 0; r < 4; ++r) {
        float v = fmaxf(acc[mi][ni][r] + bv, 0.f);
        part[mi][r][0] = fmaf(v, w30, part[mi][r][0]);
        part[mi][r][1] = fmaf(v, w31, part[mi][r][1]);
        part[mi][r][2] = fmaf(v, w32, part[mi][r][2]);
      }
  }
#pragma unroll
  for (int mi = 0; mi < 4; ++mi)
#pragma unroll
    for (int r = 0; r < 4; ++r)
#pragma unroll
      for (int j = 0; j < 3; ++j) {
        float v = part[mi][r][j];
        v += __shfl_xor(v, 1);
        v += __shfl_xor(v, 2);
        v += __shfl_xor(v, 4);
        v += __shfl_xor(v, 8);
        if (lm == 0) atomicAdd(&facc[wr + mi * 16 + q * 4 + r][j], v);
      }
  __syncthreads();
  if (t < 128) {
    const int mm = m0 + t;
    const int bb2 = mm >> 14, cc = (mm & 16383) >> 4;
    const float* xq = xf + (bb2 * 1024 + cc) * 3;
#pragma unroll
    for (int j = 0; j < 3; ++j)
      fine[(size_t)mm * 3 + j] = facc[t][j] + bc3[j] + xq[j];
  }
}

extern "C" void kernel_launch(void* const* d_in, const int* in_sizes, int n_in,
                              void* d_out, int out_size, void* d_ws, size_t ws_size,
                              hipStream_t stream) {
  const float* fea = (const float*)d_in[0];
  const float* Wl1 = (const float*)d_in[1];
  const float* bl1 = (const float*)d_in[2];
  const float* Wl2 = (const float*)d_in[3];
  const float* bl2 = (const float*)d_in[4];
  const float* Wc1 = (const float*)d_in[5];
  const float* bc1 = (const float*)d_in[6];
  const float* Wc2 = (const float*)d_in[7];
  const float* bc2 = (const float*)d_in[8];
  const float* Wc3 = (const float*)d_in[9];
  const float* bc3 = (const float*)d_in[10];
  float* xout = (float*)d_out;                // (8,1024,3)
  float* fine = (float*)d_out + 24576;        // (8,16384,3)
  char* ws = (char*)d_ws;
  float* h1  = (float*)ws;                    // 32 KB
  float* xf  = (float*)(ws + 32768);          // 96 KB
  float* gp  = (float*)(ws + 131072);         // 16 KB
  bf16*  W2T = (bf16*)(ws + 147456);          // 512 KB

  k_lin1<<<512, 256, 0, stream>>>(fea, Wl1, bl1, h1);
  k_gp<<<256, 256, 0, stream>>>(fea, Wc1, bc1, gp);
  k_w2t<<<256, 256, 0, stream>>>(Wc2, W2T);
  k_lin2<<<1536, 256, 0, stream>>>(h1, Wl2, bl2, xf, xout);
  k_gemm<<<1024, 512, 0, stream>>>(W2T, Wc1, gp, xf, bc2, Wc3, bc3, fine);
}